// Round 3
// baseline (37025.940 us; speedup 1.0000x reference)
//
#include <hip/hip_runtime.h>
#include <stdint.h>

#define B_   4096
#define H_   512
#define G4   2048      // 4*H gates
#define T_   16
#define VOC  66
#define PADT 64
#define BOST 65

// ---------------- threefry2x32 (exact JAX partitionable schedule) ----------------
__host__ __device__ inline void tf2x32(uint32_t k0, uint32_t k1,
                                       uint32_t x0, uint32_t x1,
                                       uint32_t& o0, uint32_t& o1) {
  uint32_t ks2 = k0 ^ k1 ^ 0x1BD11BDAu;
  x0 += k0; x1 += k1;
  uint32_t ks[3] = {k1, ks2, k0};
  const int R[2][4] = {{13,15,26,6},{17,29,16,24}};
#pragma unroll
  for (int i = 0; i < 5; ++i) {
    const int* r = R[i & 1];
#pragma unroll
    for (int j = 0; j < 4; ++j) {
      x0 += x1;
      x1 = (x1 << r[j]) | (x1 >> (32 - r[j]));
      x1 ^= x0;
    }
    x0 += ks[0];
    x1 += ks[1] + (uint32_t)(i + 1);
    uint32_t tmp = ks[0]; ks[0] = ks[1]; ks[1] = ks[2]; ks[2] = tmp;
  }
  o0 = x0; o1 = x1;
}

__device__ inline float sigm(float x) { return 1.0f / (1.0f + expf(-x)); }

// ---------------- prep: fused biases (gate-interleaved), WpT ----------------
__global__ void k_prep(const float* __restrict__ bih, const float* __restrict__ bhh,
                       const float* __restrict__ Wp,
                       float* __restrict__ br, float* __restrict__ WpT)
{
  int idx = blockIdx.x * 256 + threadIdx.x;
  if (idx < G4) {
    int srow = ((idx & 3) << 9) + (idx >> 2);
    br[idx] = bih[srow] + bhh[srow];
  }
  if (idx < H_ * 64) {                       // WpT[k*64+a] = Wp[a*512+k]
    int k = idx >> 6, a = idx & 63;
    WpT[idx] = Wp[a * H_ + k];
  }
}

// ---------------- tiled transpose: out[c][r] = in[perm(r)][c] ----------------
// in: logical [R][C] (perm applied to row index on read), out: [C][R]
// MODE 0: identity rows; MODE 1: gate-interleave perm srow(n)=((n&3)<<9)+(n>>2)
template<int MODE>
__global__ __launch_bounds__(256) void k_transpose(const float* __restrict__ in,
                                                   float* __restrict__ out,
                                                   int R, int C)
{
  __shared__ float tile[64][65];
  const int c0 = blockIdx.x * 64, r0 = blockIdx.y * 64;
  const int lx = threadIdx.x & 15, ly = threadIdx.x >> 4;
#pragma unroll
  for (int it = 0; it < 4; ++it) {
    int rr = ly + it * 16;
    int rlog = r0 + rr;
    int rphys = (MODE == 1) ? (((rlog & 3) << 9) + (rlog >> 2)) : rlog;
    float4 v = *(const float4*)&in[(size_t)rphys * C + c0 + lx * 4];
    tile[rr][lx * 4 + 0] = v.x; tile[rr][lx * 4 + 1] = v.y;
    tile[rr][lx * 4 + 2] = v.z; tile[rr][lx * 4 + 3] = v.w;
  }
  __syncthreads();
#pragma unroll
  for (int it = 0; it < 4; ++it) {
    int rr = ly + it * 16;
    float4 v = make_float4(tile[lx * 4 + 0][rr], tile[lx * 4 + 1][rr],
                           tile[lx * 4 + 2][rr], tile[lx * 4 + 3][rr]);
    *(float4*)&out[(size_t)(c0 + rr) * R + r0 + lx * 4] = v;
  }
}

// ---------------- embW = emb @ Wih^T, gate-interleaved columns ----------------
__global__ void k_embw(const float* __restrict__ emb, const float* __restrict__ Wih,
                       float* __restrict__ embWr)
{
  int idx = blockIdx.x * 256 + threadIdx.x;   // 66*2048
  if (idx >= VOC * G4) return;
  int a = idx >> 11, n = idx & (G4 - 1);
  int srow = ((n & 3) << 9) + (n >> 2);
  const float4* e = (const float4*)(emb + a * H_);
  const float4* w = (const float4*)(Wih + srow * H_);
  float s = 0.f;
#pragma unroll 4
  for (int k = 0; k < H_ / 4; ++k) {
    float4 ev = e[k], wv = w[k];
    s = fmaf(ev.x, wv.x, s); s = fmaf(ev.y, wv.y, s);
    s = fmaf(ev.z, wv.z, s); s = fmaf(ev.w, wv.w, s);
  }
  embWr[idx] = s;
}

// ---------------- init: c=encoded, flags ----------------
__global__ void k_init(const float* __restrict__ enc, float* __restrict__ c,
                       int* __restrict__ stopped, int* __restrict__ prevAct,
                       float* __restrict__ entSum)
{
  int i = blockIdx.x * 256 + threadIdx.x;
  if (i < B_ * H_) c[i] = enc[i];
  if (i < B_) { stopped[i] = 0; prevAct[i] = BOST; entSum[i] = 0.f; }
}

// ---------------- per-step: gates = h@Wr^T + embW[prev] + br ; fused LSTM cell ----------------
// HT: [512][4096] k-major h;  WT: [512][2048] k-major gate-interleaved Whh
// 512 threads, tile 128(M)x128(N), frag 8x4, BK=32, double-buffered LDS.
__global__ __launch_bounds__(512, 4) void k_step(
    const float* __restrict__ HT, const float* __restrict__ WT,
    const float* __restrict__ embWr, const float* __restrict__ br,
    const int* __restrict__ prevAct, float* __restrict__ C,
    float* __restrict__ Hrow, float* __restrict__ HTout)
{
  __shared__ float As[2][32][128];
  __shared__ float Bs[2][32][128];
  const int tid = threadIdx.x;
  const int tx = tid & 31, ty = tid >> 5;
  const int M0 = blockIdx.y * 128, N0 = blockIdx.x * 128;
  const int skk = tid >> 5;            // 0..15 staging row
  const int sm  = (tid & 31) * 4;      // staging col (float4)

  float acc[8][4];
#pragma unroll
  for (int i = 0; i < 8; i++)
#pragma unroll
    for (int j = 0; j < 4; j++) acc[i][j] = 0.f;

  float4 ra0, ra1, rb0, rb1;
  // prologue: load + write chunk 0
  {
    const int k0 = 0;
    ra0 = *(const float4*)&HT[(size_t)(k0 + skk) * B_ + M0 + sm];
    ra1 = *(const float4*)&HT[(size_t)(k0 + skk + 16) * B_ + M0 + sm];
    rb0 = *(const float4*)&WT[(size_t)(k0 + skk) * G4 + N0 + sm];
    rb1 = *(const float4*)&WT[(size_t)(k0 + skk + 16) * G4 + N0 + sm];
    *(float4*)&As[0][skk][sm] = ra0;
    *(float4*)&As[0][skk + 16][sm] = ra1;
    *(float4*)&Bs[0][skk][sm] = rb0;
    *(float4*)&Bs[0][skk + 16][sm] = rb1;
  }

  int cur = 0;
  for (int t = 0; t < 16; ++t) {
    __syncthreads();
    if (t < 15) {
      const int k0 = (t + 1) * 32;
      ra0 = *(const float4*)&HT[(size_t)(k0 + skk) * B_ + M0 + sm];
      ra1 = *(const float4*)&HT[(size_t)(k0 + skk + 16) * B_ + M0 + sm];
      rb0 = *(const float4*)&WT[(size_t)(k0 + skk) * G4 + N0 + sm];
      rb1 = *(const float4*)&WT[(size_t)(k0 + skk + 16) * G4 + N0 + sm];
    }
#pragma unroll
    for (int kk = 0; kk < 32; ++kk) {
      const float4 a0 = *(const float4*)&As[cur][kk][ty * 8];
      const float4 a1 = *(const float4*)&As[cur][kk][ty * 8 + 4];
      const float4 b  = *(const float4*)&Bs[cur][kk][tx * 4];
      const float av[8] = {a0.x, a0.y, a0.z, a0.w, a1.x, a1.y, a1.z, a1.w};
      const float bv[4] = {b.x, b.y, b.z, b.w};
#pragma unroll
      for (int i = 0; i < 8; i++)
#pragma unroll
        for (int j = 0; j < 4; j++) acc[i][j] = fmaf(av[i], bv[j], acc[i][j]);
    }
    if (t < 15) {
      const int nb = cur ^ 1;
      *(float4*)&As[nb][skk][sm] = ra0;
      *(float4*)&As[nb][skk + 16][sm] = ra1;
      *(float4*)&Bs[nb][skk][sm] = rb0;
      *(float4*)&Bs[nb][skk + 16][sm] = rb1;
    }
    cur ^= 1;
  }

  // epilogue: add input-gate rows + biases, LSTM cell, write c, h (row + transposed)
  const int u = (N0 >> 2) + tx;
  const int n0 = N0 + tx * 4;
  const float4 brv = *(const float4*)&br[n0];
  float hn8[8];
#pragma unroll
  for (int i = 0; i < 8; ++i) {
    const int row = M0 + ty * 8 + i;
    const float4 ew = *(const float4*)&embWr[(size_t)prevAct[row] * G4 + n0];
    const float ig = acc[i][0] + ew.x + brv.x;
    const float fg = acc[i][1] + ew.y + brv.y;
    const float gg = acc[i][2] + ew.z + brv.z;
    const float og = acc[i][3] + ew.w + brv.w;
    const float cp = C[(size_t)row * H_ + u];
    const float cn = sigm(fg) * cp + sigm(ig) * tanhf(gg);
    const float hn = sigm(og) * tanhf(cn);
    C[(size_t)row * H_ + u] = cn;
    Hrow[(size_t)row * H_ + u] = hn;
    hn8[i] = hn;
  }
  const int mrow = M0 + ty * 8;
  *(float4*)&HTout[(size_t)u * B_ + mrow] = make_float4(hn8[0], hn8[1], hn8[2], hn8[3]);
  *(float4*)&HTout[(size_t)u * B_ + mrow + 4] = make_float4(hn8[4], hn8[5], hn8[6], hn8[7]);
}

// ---------------- per-step: logits, log-softmax, gumbel sample, outputs ----------------
__global__ __launch_bounds__(256) void k_sample(
    const float* __restrict__ Hnew, const float* __restrict__ WpT,
    const float* __restrict__ bp, float* __restrict__ out_msg,
    float* __restrict__ out_lp, int* __restrict__ stopped,
    int* __restrict__ prevAct, float* __restrict__ entSum,
    uint32_t key0, uint32_t key1, int t)
{
  const int lane = threadIdx.x & 63;
  const int b = blockIdx.x * 4 + (threadIdx.x >> 6);
  const float* hrow = Hnew + (size_t)b * H_;

  float acc = 0.f;
#pragma unroll 4
  for (int k4 = 0; k4 < H_; k4 += 4) {
    float4 hv = *(const float4*)(hrow + k4);
    acc = fmaf(hv.x, WpT[(k4 + 0) * 64 + lane], acc);
    acc = fmaf(hv.y, WpT[(k4 + 1) * 64 + lane], acc);
    acc = fmaf(hv.z, WpT[(k4 + 2) * 64 + lane], acc);
    acc = fmaf(hv.w, WpT[(k4 + 3) * 64 + lane], acc);
  }
  acc += bp[lane];                          // logits[b][lane]

  // log_softmax
  float m = acc;
#pragma unroll
  for (int o = 32; o > 0; o >>= 1) m = fmaxf(m, __shfl_xor(m, o, 64));
  float ex = expf(acc - m);
  float s = ex;
#pragma unroll
  for (int o = 32; o > 0; o >>= 1) s += __shfl_xor(s, o, 64);
  float logp = (acc - m) - logf(s);
  float p = expf(logp);
  float pe = p * logp;
  float es = pe;
#pragma unroll
  for (int o = 32; o > 0; o >>= 1) es += __shfl_xor(es, o, 64);
  float ent = -es;

  // gumbel: JAX partitionable threefry — 64-bit counter (0, j), bits = o0 ^ o1
  uint32_t j = (uint32_t)(b * 64 + lane);
  uint32_t o0, o1; tf2x32(key0, key1, 0u, j, o0, o1);
  uint32_t bits = o0 ^ o1;
  float f = __uint_as_float(0x3F800000u | (bits >> 9)) - 1.0f;
  const float TINY = 1.17549435e-38f;
  float u = fmaxf(TINY, f + TINY);
  float gum = -logf(-logf(u));
  float z = gum + acc;

  // argmax, first-index tie-break
  float best = z; int bi = lane;
#pragma unroll
  for (int o = 32; o > 0; o >>= 1) {
    float ov = __shfl_xor(best, o, 64);
    int oi = __shfl_xor(bi, o, 64);
    if (ov > best || (ov == best && oi < bi)) { best = ov; bi = oi; }
  }
  float lpa = __shfl(logp, bi, 64);

  if (lane == 0) {
    int st = stopped[b];
    float live = st ? 0.f : 1.f;
    int act = st ? PADT : bi;
    out_msg[(size_t)b * T_ + t] = (float)act;
    out_lp[(size_t)b * T_ + t] = live * lpa;
    entSum[b] += live * ent;
    stopped[b] = st | (act == 0);
    prevAct[b] = act;
  }
}

// ---------------- final: msg_len, ent_avg ----------------
__global__ void k_final(const float* __restrict__ out_msg, const float* __restrict__ entSum,
                        float* __restrict__ out_len, float* __restrict__ out_ent)
{
  int b = blockIdx.x * 256 + threadIdx.x;
  if (b >= B_) return;
  int cnt = 0;
#pragma unroll
  for (int t = 0; t < T_; t++) cnt += (out_msg[(size_t)b * T_ + t] != 64.0f) ? 1 : 0;
  out_len[b] = (float)cnt;
  out_ent[b] = entSum[b] / (float)cnt;
}

extern "C" void kernel_launch(void* const* d_in, const int* in_sizes, int n_in,
                              void* d_out, int out_size, void* d_ws, size_t ws_size,
                              hipStream_t stream)
{
  const float* enc = (const float*)d_in[0];
  const float* emb = (const float*)d_in[1];
  const float* Wih = (const float*)d_in[2];
  const float* Whh = (const float*)d_in[3];
  const float* bih = (const float*)d_in[4];
  const float* bhh = (const float*)d_in[5];
  const float* Wp  = (const float*)d_in[6];
  const float* bp  = (const float*)d_in[7];

  float* out_msg = (float*)d_out;            // [4096*16]
  float* out_len = out_msg + B_ * T_;        // [4096]
  float* out_lp  = out_len + B_;             // [4096*16]
  float* out_ent = out_lp + B_ * T_;         // [4096]

  float* w = (float*)d_ws;
  float* WrT   = w;  w += H_ * G4;           // [512][2048] 4MB
  float* embWr = w;  w += VOC * G4;
  float* br    = w;  w += G4;
  float* WpT   = w;  w += H_ * 64;
  float* hTA   = w;  w += H_ * B_;           // [512][4096] 8MB
  float* hTB   = w;  w += H_ * B_;           // 8MB
  float* hRow  = w;  w += B_ * H_;           // row-major h for sampling, 8MB
  float* cbuf  = w;  w += B_ * H_;           // 8MB
  float* entS  = w;  w += B_;
  int* stopped = (int*)w;  w += B_;
  int* prevAct = (int*)w;  w += B_;

  // step keys: partitionable threefry split — key[t] = threefry2x32((0,42), (0, t))
  uint32_t k0s[T_], k1s[T_];
  for (int t = 0; t < T_; t++) {
    uint32_t a, b2;
    tf2x32(0u, 42u, 0u, (uint32_t)t, a, b2);
    k0s[t] = a; k1s[t] = b2;
  }

  hipLaunchKernelGGL(k_prep, dim3((H_ * 64 + 255) / 256), dim3(256), 0, stream,
                     bih, bhh, Wp, br, WpT);
  hipLaunchKernelGGL(k_embw, dim3((VOC * G4 + 255) / 256), dim3(256), 0, stream,
                     emb, Wih, embWr);
  // WrT[k][n] = Whh[srow(n)][k]   (gate-interleaved, k-major)
  hipLaunchKernelGGL((k_transpose<1>), dim3(H_ / 64, G4 / 64), dim3(256), 0, stream,
                     Whh, WrT, G4, H_);
  // hTA[k][m] = enc[m][k]
  hipLaunchKernelGGL((k_transpose<0>), dim3(H_ / 64, B_ / 64), dim3(256), 0, stream,
                     enc, hTA, B_, H_);
  hipLaunchKernelGGL(k_init, dim3((B_ * H_ + 255) / 256), dim3(256), 0, stream,
                     enc, cbuf, stopped, prevAct, entS);

  for (int t = 0; t < T_; t++) {
    const float* hTin = (t & 1) ? hTB : hTA;
    float* hTout = (t & 1) ? hTA : hTB;
    hipLaunchKernelGGL(k_step, dim3(G4 / 128, B_ / 128), dim3(512), 0, stream,
                       hTin, WrT, embWr, br, prevAct, cbuf, hRow, hTout);
    hipLaunchKernelGGL(k_sample, dim3(B_ / 4), dim3(256), 0, stream,
                       hRow, WpT, bp, out_msg, out_lp, stopped, prevAct, entS,
                       k0s[t], k1s[t], t);
  }
  hipLaunchKernelGGL(k_final, dim3(B_ / 256), dim3(256), 0, stream,
                     out_msg, entS, out_len, out_ent);
}

// Round 4
// 17813.100 us; speedup vs baseline: 2.0786x; 2.0786x over previous
//
#include <hip/hip_runtime.h>
#include <stdint.h>

#define B_   4096
#define H_   512
#define G4   2048      // 4*H gates
#define T_   16
#define VOC  66
#define PADT 64
#define BOST 65

// ---------------- threefry2x32 (exact JAX partitionable schedule) ----------------
__host__ __device__ inline void tf2x32(uint32_t k0, uint32_t k1,
                                       uint32_t x0, uint32_t x1,
                                       uint32_t& o0, uint32_t& o1) {
  uint32_t ks2 = k0 ^ k1 ^ 0x1BD11BDAu;
  x0 += k0; x1 += k1;
  uint32_t ks[3] = {k1, ks2, k0};
  const int R[2][4] = {{13,15,26,6},{17,29,16,24}};
#pragma unroll
  for (int i = 0; i < 5; ++i) {
    const int* r = R[i & 1];
#pragma unroll
    for (int j = 0; j < 4; ++j) {
      x0 += x1;
      x1 = (x1 << r[j]) | (x1 >> (32 - r[j]));
      x1 ^= x0;
    }
    x0 += ks[0];
    x1 += ks[1] + (uint32_t)(i + 1);
    uint32_t tmp = ks[0]; ks[0] = ks[1]; ks[1] = ks[2]; ks[2] = tmp;
  }
  o0 = x0; o1 = x1;
}

__device__ inline float sigm(float x) { return 1.0f / (1.0f + expf(-x)); }

// ---------------- prep: fused biases (gate-interleaved), WpT ----------------
__global__ void k_prep(const float* __restrict__ bih, const float* __restrict__ bhh,
                       const float* __restrict__ Wp,
                       float* __restrict__ br, float* __restrict__ WpT)
{
  int idx = blockIdx.x * 256 + threadIdx.x;
  if (idx < G4) {
    int srow = ((idx & 3) << 9) + (idx >> 2);
    br[idx] = bih[srow] + bhh[srow];
  }
  if (idx < H_ * 64) {                       // WpT[k*64+a] = Wp[a*512+k]
    int k = idx >> 6, a = idx & 63;
    WpT[idx] = Wp[a * H_ + k];
  }
}

// ---------------- tiled transpose: out[c][r] = in[perm(r)][c] ----------------
// MODE 0: identity rows; MODE 1: gate-interleave perm srow(n)=((n&3)<<9)+(n>>2)
template<int MODE>
__global__ __launch_bounds__(256) void k_transpose(const float* __restrict__ in,
                                                   float* __restrict__ out,
                                                   int R, int C)
{
  __shared__ float tile[64][65];
  const int c0 = blockIdx.x * 64, r0 = blockIdx.y * 64;
  const int lx = threadIdx.x & 15, ly = threadIdx.x >> 4;
#pragma unroll
  for (int it = 0; it < 4; ++it) {
    int rr = ly + it * 16;
    int rlog = r0 + rr;
    int rphys = (MODE == 1) ? (((rlog & 3) << 9) + (rlog >> 2)) : rlog;
    float4 v = *(const float4*)&in[(size_t)rphys * C + c0 + lx * 4];
    tile[rr][lx * 4 + 0] = v.x; tile[rr][lx * 4 + 1] = v.y;
    tile[rr][lx * 4 + 2] = v.z; tile[rr][lx * 4 + 3] = v.w;
  }
  __syncthreads();
#pragma unroll
  for (int it = 0; it < 4; ++it) {
    int rr = ly + it * 16;
    float4 v = make_float4(tile[lx * 4 + 0][rr], tile[lx * 4 + 1][rr],
                           tile[lx * 4 + 2][rr], tile[lx * 4 + 3][rr]);
    *(float4*)&out[(size_t)(c0 + rr) * R + r0 + lx * 4] = v;
  }
}

// ---------------- embW = emb @ Wih^T, gate-interleaved columns ----------------
__global__ void k_embw(const float* __restrict__ emb, const float* __restrict__ Wih,
                       float* __restrict__ embWr)
{
  int idx = blockIdx.x * 256 + threadIdx.x;   // 66*2048
  if (idx >= VOC * G4) return;
  int a = idx >> 11, n = idx & (G4 - 1);
  int srow = ((n & 3) << 9) + (n >> 2);
  const float4* e = (const float4*)(emb + a * H_);
  const float4* w = (const float4*)(Wih + srow * H_);
  float s = 0.f;
#pragma unroll 4
  for (int k = 0; k < H_ / 4; ++k) {
    float4 ev = e[k], wv = w[k];
    s = fmaf(ev.x, wv.x, s); s = fmaf(ev.y, wv.y, s);
    s = fmaf(ev.z, wv.z, s); s = fmaf(ev.w, wv.w, s);
  }
  embWr[idx] = s;
}

// ---------------- init: c=encoded, flags ----------------
__global__ void k_init(const float* __restrict__ enc, float* __restrict__ c,
                       int* __restrict__ stopped, int* __restrict__ prevAct,
                       float* __restrict__ entSum)
{
  int i = blockIdx.x * 256 + threadIdx.x;
  if (i < B_ * H_) c[i] = enc[i];
  if (i < B_) { stopped[i] = 0; prevAct[i] = BOST; entSum[i] = 0.f; }
}

// ---------------- per-step: gates = h@Wr^T + embW[prev] + br ; fused LSTM cell ----------------
// HT: [512][4096] k-major h;  WT: [512][2048] k-major gate-interleaved Whh
// 512 threads, tile 128(M)x128(N), frag 8x4, BK=32, double-buffered LDS.
// launch_bounds (512,2): ~80 live VGPRs must NOT spill (round-3 lesson: (512,4)
// capped VGPR at 64 -> 5 GB scratch writes, 17-300x slowdown).
__global__ __launch_bounds__(512, 2) void k_step(
    const float* __restrict__ HT, const float* __restrict__ WT,
    const float* __restrict__ embWr, const float* __restrict__ br,
    const int* __restrict__ prevAct, float* __restrict__ C,
    float* __restrict__ Hrow, float* __restrict__ HTout)
{
  __shared__ float As[2][32][128];
  __shared__ float Bs[2][32][128];
  const int tid = threadIdx.x;
  const int tx = tid & 31, ty = tid >> 5;
  const int M0 = blockIdx.y * 128, N0 = blockIdx.x * 128;
  const int skk = tid >> 5;            // 0..15 staging row
  const int sm  = (tid & 31) * 4;      // staging col (float4)

  float acc[8][4];
#pragma unroll
  for (int i = 0; i < 8; i++)
#pragma unroll
    for (int j = 0; j < 4; j++) acc[i][j] = 0.f;

  float4 ra0, ra1, rb0, rb1;
  // prologue: load + write chunk 0
  {
    const int k0 = 0;
    ra0 = *(const float4*)&HT[(size_t)(k0 + skk) * B_ + M0 + sm];
    ra1 = *(const float4*)&HT[(size_t)(k0 + skk + 16) * B_ + M0 + sm];
    rb0 = *(const float4*)&WT[(size_t)(k0 + skk) * G4 + N0 + sm];
    rb1 = *(const float4*)&WT[(size_t)(k0 + skk + 16) * G4 + N0 + sm];
    *(float4*)&As[0][skk][sm] = ra0;
    *(float4*)&As[0][skk + 16][sm] = ra1;
    *(float4*)&Bs[0][skk][sm] = rb0;
    *(float4*)&Bs[0][skk + 16][sm] = rb1;
  }

  int cur = 0;
  for (int t = 0; t < 16; ++t) {
    __syncthreads();
    if (t < 15) {
      const int k0 = (t + 1) * 32;
      ra0 = *(const float4*)&HT[(size_t)(k0 + skk) * B_ + M0 + sm];
      ra1 = *(const float4*)&HT[(size_t)(k0 + skk + 16) * B_ + M0 + sm];
      rb0 = *(const float4*)&WT[(size_t)(k0 + skk) * G4 + N0 + sm];
      rb1 = *(const float4*)&WT[(size_t)(k0 + skk + 16) * G4 + N0 + sm];
    }
#pragma unroll
    for (int kk = 0; kk < 32; ++kk) {
      const float4 a0 = *(const float4*)&As[cur][kk][ty * 8];
      const float4 a1 = *(const float4*)&As[cur][kk][ty * 8 + 4];
      const float4 b  = *(const float4*)&Bs[cur][kk][tx * 4];
      const float av[8] = {a0.x, a0.y, a0.z, a0.w, a1.x, a1.y, a1.z, a1.w};
      const float bv[4] = {b.x, b.y, b.z, b.w};
#pragma unroll
      for (int i = 0; i < 8; i++)
#pragma unroll
        for (int j = 0; j < 4; j++) acc[i][j] = fmaf(av[i], bv[j], acc[i][j]);
    }
    if (t < 15) {
      const int nb = cur ^ 1;
      *(float4*)&As[nb][skk][sm] = ra0;
      *(float4*)&As[nb][skk + 16][sm] = ra1;
      *(float4*)&Bs[nb][skk][sm] = rb0;
      *(float4*)&Bs[nb][skk + 16][sm] = rb1;
    }
    cur ^= 1;
  }

  // epilogue: add input-gate rows + biases, LSTM cell, write c, h (row + transposed)
  const int u = (N0 >> 2) + tx;
  const int n0 = N0 + tx * 4;
  const float4 brv = *(const float4*)&br[n0];
  float hn8[8];
#pragma unroll
  for (int i = 0; i < 8; ++i) {
    const int row = M0 + ty * 8 + i;
    const float4 ew = *(const float4*)&embWr[(size_t)prevAct[row] * G4 + n0];
    const float ig = acc[i][0] + ew.x + brv.x;
    const float fg = acc[i][1] + ew.y + brv.y;
    const float gg = acc[i][2] + ew.z + brv.z;
    const float og = acc[i][3] + ew.w + brv.w;
    const float cp = C[(size_t)row * H_ + u];
    const float cn = sigm(fg) * cp + sigm(ig) * tanhf(gg);
    const float hn = sigm(og) * tanhf(cn);
    C[(size_t)row * H_ + u] = cn;
    Hrow[(size_t)row * H_ + u] = hn;
    hn8[i] = hn;
  }
  const int mrow = M0 + ty * 8;
  *(float4*)&HTout[(size_t)u * B_ + mrow] = make_float4(hn8[0], hn8[1], hn8[2], hn8[3]);
  *(float4*)&HTout[(size_t)u * B_ + mrow + 4] = make_float4(hn8[4], hn8[5], hn8[6], hn8[7]);
}

// ---------------- per-step: logits, log-softmax, gumbel sample, outputs ----------------
__global__ __launch_bounds__(256) void k_sample(
    const float* __restrict__ Hnew, const float* __restrict__ WpT,
    const float* __restrict__ bp, float* __restrict__ out_msg,
    float* __restrict__ out_lp, int* __restrict__ stopped,
    int* __restrict__ prevAct, float* __restrict__ entSum,
    uint32_t key0, uint32_t key1, int t)
{
  const int lane = threadIdx.x & 63;
  const int b = blockIdx.x * 4 + (threadIdx.x >> 6);
  const float* hrow = Hnew + (size_t)b * H_;

  float acc = 0.f;
#pragma unroll 4
  for (int k4 = 0; k4 < H_; k4 += 4) {
    float4 hv = *(const float4*)(hrow + k4);
    acc = fmaf(hv.x, WpT[(k4 + 0) * 64 + lane], acc);
    acc = fmaf(hv.y, WpT[(k4 + 1) * 64 + lane], acc);
    acc = fmaf(hv.z, WpT[(k4 + 2) * 64 + lane], acc);
    acc = fmaf(hv.w, WpT[(k4 + 3) * 64 + lane], acc);
  }
  acc += bp[lane];                          // logits[b][lane]

  // log_softmax
  float m = acc;
#pragma unroll
  for (int o = 32; o > 0; o >>= 1) m = fmaxf(m, __shfl_xor(m, o, 64));
  float ex = expf(acc - m);
  float s = ex;
#pragma unroll
  for (int o = 32; o > 0; o >>= 1) s += __shfl_xor(s, o, 64);
  float logp = (acc - m) - logf(s);
  float p = expf(logp);
  float pe = p * logp;
  float es = pe;
#pragma unroll
  for (int o = 32; o > 0; o >>= 1) es += __shfl_xor(es, o, 64);
  float ent = -es;

  // gumbel: JAX partitionable threefry — 64-bit counter (0, j), bits = o0 ^ o1
  uint32_t j = (uint32_t)(b * 64 + lane);
  uint32_t o0, o1; tf2x32(key0, key1, 0u, j, o0, o1);
  uint32_t bits = o0 ^ o1;
  float f = __uint_as_float(0x3F800000u | (bits >> 9)) - 1.0f;
  const float TINY = 1.17549435e-38f;
  float u = fmaxf(TINY, f + TINY);
  float gum = -logf(-logf(u));
  float z = gum + acc;

  // argmax, first-index tie-break
  float best = z; int bi = lane;
#pragma unroll
  for (int o = 32; o > 0; o >>= 1) {
    float ov = __shfl_xor(best, o, 64);
    int oi = __shfl_xor(bi, o, 64);
    if (ov > best || (ov == best && oi < bi)) { best = ov; bi = oi; }
  }
  float lpa = __shfl(logp, bi, 64);

  if (lane == 0) {
    int st = stopped[b];
    float live = st ? 0.f : 1.f;
    int act = st ? PADT : bi;
    out_msg[(size_t)b * T_ + t] = (float)act;
    out_lp[(size_t)b * T_ + t] = live * lpa;
    entSum[b] += live * ent;
    stopped[b] = st | (act == 0);
    prevAct[b] = act;
  }
}

// ---------------- final: msg_len, ent_avg ----------------
__global__ void k_final(const float* __restrict__ out_msg, const float* __restrict__ entSum,
                        float* __restrict__ out_len, float* __restrict__ out_ent)
{
  int b = blockIdx.x * 256 + threadIdx.x;
  if (b >= B_) return;
  int cnt = 0;
#pragma unroll
  for (int t = 0; t < T_; t++) cnt += (out_msg[(size_t)b * T_ + t] != 64.0f) ? 1 : 0;
  out_len[b] = (float)cnt;
  out_ent[b] = entSum[b] / (float)cnt;
}

extern "C" void kernel_launch(void* const* d_in, const int* in_sizes, int n_in,
                              void* d_out, int out_size, void* d_ws, size_t ws_size,
                              hipStream_t stream)
{
  const float* enc = (const float*)d_in[0];
  const float* emb = (const float*)d_in[1];
  const float* Wih = (const float*)d_in[2];
  const float* Whh = (const float*)d_in[3];
  const float* bih = (const float*)d_in[4];
  const float* bhh = (const float*)d_in[5];
  const float* Wp  = (const float*)d_in[6];
  const float* bp  = (const float*)d_in[7];

  float* out_msg = (float*)d_out;            // [4096*16]
  float* out_len = out_msg + B_ * T_;        // [4096]
  float* out_lp  = out_len + B_;             // [4096*16]
  float* out_ent = out_lp + B_ * T_;         // [4096]

  float* w = (float*)d_ws;
  float* WrT   = w;  w += H_ * G4;           // [512][2048] 4MB
  float* embWr = w;  w += VOC * G4;
  float* br    = w;  w += G4;
  float* WpT   = w;  w += H_ * 64;
  float* hTA   = w;  w += H_ * B_;           // [512][4096] 8MB
  float* hTB   = w;  w += H_ * B_;           // 8MB
  float* hRow  = w;  w += B_ * H_;           // row-major h for sampling, 8MB
  float* cbuf  = w;  w += B_ * H_;           // 8MB
  float* entS  = w;  w += B_;
  int* stopped = (int*)w;  w += B_;
  int* prevAct = (int*)w;  w += B_;

  // step keys: partitionable threefry split — key[t] = threefry2x32((0,42), (0, t))
  uint32_t k0s[T_], k1s[T_];
  for (int t = 0; t < T_; t++) {
    uint32_t a, b2;
    tf2x32(0u, 42u, 0u, (uint32_t)t, a, b2);
    k0s[t] = a; k1s[t] = b2;
  }

  hipLaunchKernelGGL(k_prep, dim3((H_ * 64 + 255) / 256), dim3(256), 0, stream,
                     bih, bhh, Wp, br, WpT);
  hipLaunchKernelGGL(k_embw, dim3((VOC * G4 + 255) / 256), dim3(256), 0, stream,
                     emb, Wih, embWr);
  // WrT[k][n] = Whh[srow(n)][k]   (gate-interleaved, k-major)
  hipLaunchKernelGGL((k_transpose<1>), dim3(H_ / 64, G4 / 64), dim3(256), 0, stream,
                     Whh, WrT, G4, H_);
  // hTA[k][m] = enc[m][k]
  hipLaunchKernelGGL((k_transpose<0>), dim3(H_ / 64, B_ / 64), dim3(256), 0, stream,
                     enc, hTA, B_, H_);
  hipLaunchKernelGGL(k_init, dim3((B_ * H_ + 255) / 256), dim3(256), 0, stream,
                     enc, cbuf, stopped, prevAct, entS);

  for (int t = 0; t < T_; t++) {
    const float* hTin = (t & 1) ? hTB : hTA;
    float* hTout = (t & 1) ? hTA : hTB;
    hipLaunchKernelGGL(k_step, dim3(G4 / 128, B_ / 128), dim3(512), 0, stream,
                       hTin, WrT, embWr, br, prevAct, cbuf, hRow, hTout);
    hipLaunchKernelGGL(k_sample, dim3(B_ / 4), dim3(256), 0, stream,
                       hRow, WpT, bp, out_msg, out_lp, stopped, prevAct, entS,
                       k0s[t], k1s[t], t);
  }
  hipLaunchKernelGGL(k_final, dim3(B_ / 256), dim3(256), 0, stream,
                     out_msg, entS, out_len, out_ent);
}

// Round 5
// 3034.698 us; speedup vs baseline: 12.2009x; 5.8698x over previous
//
#include <hip/hip_runtime.h>
#include <stdint.h>

#define B_   4096
#define H_   512
#define G4   2048      // 4*H gates
#define T_   16
#define VOC  66
#define PADT 64
#define BOST 65

// ---------------- threefry2x32 (exact JAX partitionable schedule) ----------------
__host__ __device__ inline void tf2x32(uint32_t k0, uint32_t k1,
                                       uint32_t x0, uint32_t x1,
                                       uint32_t& o0, uint32_t& o1) {
  uint32_t ks2 = k0 ^ k1 ^ 0x1BD11BDAu;
  x0 += k0; x1 += k1;
  uint32_t ks[3] = {k1, ks2, k0};
  const int R[2][4] = {{13,15,26,6},{17,29,16,24}};
#pragma unroll
  for (int i = 0; i < 5; ++i) {
    const int* r = R[i & 1];
#pragma unroll
    for (int j = 0; j < 4; ++j) {
      x0 += x1;
      x1 = (x1 << r[j]) | (x1 >> (32 - r[j]));
      x1 ^= x0;
    }
    x0 += ks[0];
    x1 += ks[1] + (uint32_t)(i + 1);
    uint32_t tmp = ks[0]; ks[0] = ks[1]; ks[1] = ks[2]; ks[2] = tmp;
  }
  o0 = x0; o1 = x1;
}

__device__ inline float sigm(float x) { return 1.0f / (1.0f + expf(-x)); }

// ---------------- prep: fused biases (gate-interleaved), WpT ----------------
__global__ void k_prep(const float* __restrict__ bih, const float* __restrict__ bhh,
                       const float* __restrict__ Wp,
                       float* __restrict__ br, float* __restrict__ WpT)
{
  int idx = blockIdx.x * 256 + threadIdx.x;
  if (idx < G4) {
    int srow = ((idx & 3) << 9) + (idx >> 2);
    br[idx] = bih[srow] + bhh[srow];
  }
  if (idx < H_ * 64) {                       // WpT[k*64+a] = Wp[a*512+k]
    int k = idx >> 6, a = idx & 63;
    WpT[idx] = Wp[a * H_ + k];
  }
}

// ---------------- tiled transpose: out[c][r] = in[perm(r)][c] ----------------
// MODE 0: identity rows; MODE 1: gate-interleave perm srow(n)=((n&3)<<9)+(n>>2)
template<int MODE>
__global__ __launch_bounds__(256) void k_transpose(const float* __restrict__ in,
                                                   float* __restrict__ out,
                                                   int R, int C)
{
  __shared__ float tile[64][65];
  const int c0 = blockIdx.x * 64, r0 = blockIdx.y * 64;
  const int lx = threadIdx.x & 15, ly = threadIdx.x >> 4;
#pragma unroll
  for (int it = 0; it < 4; ++it) {
    int rr = ly + it * 16;
    int rlog = r0 + rr;
    int rphys = (MODE == 1) ? (((rlog & 3) << 9) + (rlog >> 2)) : rlog;
    float4 v = *(const float4*)&in[(size_t)rphys * C + c0 + lx * 4];
    tile[rr][lx * 4 + 0] = v.x; tile[rr][lx * 4 + 1] = v.y;
    tile[rr][lx * 4 + 2] = v.z; tile[rr][lx * 4 + 3] = v.w;
  }
  __syncthreads();
#pragma unroll
  for (int it = 0; it < 4; ++it) {
    int rr = ly + it * 16;
    float4 v = make_float4(tile[lx * 4 + 0][rr], tile[lx * 4 + 1][rr],
                           tile[lx * 4 + 2][rr], tile[lx * 4 + 3][rr]);
    *(float4*)&out[(size_t)(c0 + rr) * R + r0 + lx * 4] = v;
  }
}

// ---------------- embW = emb @ Wih^T, gate-interleaved columns ----------------
__global__ void k_embw(const float* __restrict__ emb, const float* __restrict__ Wih,
                       float* __restrict__ embWr)
{
  int idx = blockIdx.x * 256 + threadIdx.x;   // 66*2048
  if (idx >= VOC * G4) return;
  int a = idx >> 11, n = idx & (G4 - 1);
  int srow = ((n & 3) << 9) + (n >> 2);
  const float4* e = (const float4*)(emb + a * H_);
  const float4* w = (const float4*)(Wih + srow * H_);
  float s = 0.f;
#pragma unroll 4
  for (int k = 0; k < H_ / 4; ++k) {
    float4 ev = e[k], wv = w[k];
    s = fmaf(ev.x, wv.x, s); s = fmaf(ev.y, wv.y, s);
    s = fmaf(ev.z, wv.z, s); s = fmaf(ev.w, wv.w, s);
  }
  embWr[idx] = s;
}

// ---------------- init: c=encoded, flags ----------------
__global__ void k_init(const float* __restrict__ enc, float* __restrict__ c,
                       int* __restrict__ stopped, int* __restrict__ prevAct,
                       float* __restrict__ entSum)
{
  int i = blockIdx.x * 256 + threadIdx.x;
  if (i < B_ * H_) c[i] = enc[i];
  if (i < B_) { stopped[i] = 0; prevAct[i] = BOST; entSum[i] = 0.f; }
}

// ---------------- per-step: gates = h@Wr^T + embW[prev] + br ; fused LSTM cell ----------------
// HT: [512][4096] k-major h;  WT: [512][2048] k-major gate-interleaved Whh
// 256 threads (round-2's proven no-spill engine), tile 128x128, frag 8x8 in
// split halves (cols tx*4 and tx*4+64 -> all LDS reads are aligned b128,
// <=2-way bank aliasing). BK=16, double-buffered LDS (32 KB).
// NO min-occupancy launch_bounds (round-3/4 lesson: forcing it spills acc ->
// GBs of scratch traffic). #pragma unroll 1 on K-loop to stop full unroll.
__global__ __launch_bounds__(256) void k_step(
    const float* __restrict__ HT, const float* __restrict__ WT,
    const float* __restrict__ embWr, const float* __restrict__ br,
    const int* __restrict__ prevAct, float* __restrict__ C,
    float* __restrict__ Hrow, float* __restrict__ HTout)
{
  __shared__ float As[2][16][128];
  __shared__ float Bs[2][16][128];
  const int tid = threadIdx.x;
  const int tx = tid & 15;         // N-fragment slot
  const int ty = tid >> 4;         // M-fragment slot
  const int M0 = blockIdx.y * 128, N0 = blockIdx.x * 128;
  const int skk = tid >> 4;        // staging row 0..15
  const int sc  = (tid & 15) * 4;  // staging col; halves at sc and sc+64

  float acc[8][8];
#pragma unroll
  for (int i = 0; i < 8; i++)
#pragma unroll
    for (int j = 0; j < 8; j++) acc[i][j] = 0.f;

  float4 ra0, ra1, rb0, rb1;
  // prologue: chunk 0
  ra0 = *(const float4*)&HT[(size_t)skk * B_ + M0 + sc];
  ra1 = *(const float4*)&HT[(size_t)skk * B_ + M0 + sc + 64];
  rb0 = *(const float4*)&WT[(size_t)skk * G4 + N0 + sc];
  rb1 = *(const float4*)&WT[(size_t)skk * G4 + N0 + sc + 64];
  *(float4*)&As[0][skk][sc]      = ra0;
  *(float4*)&As[0][skk][sc + 64] = ra1;
  *(float4*)&Bs[0][skk][sc]      = rb0;
  *(float4*)&Bs[0][skk][sc + 64] = rb1;

  int cur = 0;
#pragma unroll 1
  for (int t = 0; t < 32; ++t) {
    __syncthreads();
    if (t < 31) {
      const int k0 = (t + 1) * 16 + skk;
      ra0 = *(const float4*)&HT[(size_t)k0 * B_ + M0 + sc];
      ra1 = *(const float4*)&HT[(size_t)k0 * B_ + M0 + sc + 64];
      rb0 = *(const float4*)&WT[(size_t)k0 * G4 + N0 + sc];
      rb1 = *(const float4*)&WT[(size_t)k0 * G4 + N0 + sc + 64];
    }
#pragma unroll
    for (int kk = 0; kk < 16; ++kk) {
      const float4 a0 = *(const float4*)&As[cur][kk][ty * 4];
      const float4 a1 = *(const float4*)&As[cur][kk][ty * 4 + 64];
      const float4 b0 = *(const float4*)&Bs[cur][kk][tx * 4];
      const float4 b1 = *(const float4*)&Bs[cur][kk][tx * 4 + 64];
      const float av[8] = {a0.x, a0.y, a0.z, a0.w, a1.x, a1.y, a1.z, a1.w};
      const float bv[8] = {b0.x, b0.y, b0.z, b0.w, b1.x, b1.y, b1.z, b1.w};
#pragma unroll
      for (int i = 0; i < 8; i++)
#pragma unroll
        for (int j = 0; j < 8; j++) acc[i][j] = fmaf(av[i], bv[j], acc[i][j]);
    }
    if (t < 31) {
      const int nb = cur ^ 1;
      *(float4*)&As[nb][skk][sc]      = ra0;
      *(float4*)&As[nb][skk][sc + 64] = ra1;
      *(float4*)&Bs[nb][skk][sc]      = rb0;
      *(float4*)&Bs[nb][skk][sc + 64] = rb1;
    }
    cur ^= 1;
  }

  // epilogue: gates -> LSTM cell -> C, Hrow, HTout
  // cols: N0+tx*4+{0..3} => u = uA;  N0+64+tx*4+{0..3} => u = uB
  // rows: M0+ty*4+{0..3} (i=0..3);   M0+64+ty*4+{0..3} (i=4..7)
  const int uA = (N0 >> 2) + tx;
  const int uB = uA + 16;
  const float4 brA = *(const float4*)&br[N0 + tx * 4];
  const float4 brB = *(const float4*)&br[N0 + 64 + tx * 4];
  float hnA[8], hnB[8];
#pragma unroll
  for (int i = 0; i < 8; ++i) {
    const int row = M0 + ((i < 4) ? (ty * 4 + i) : (64 + ty * 4 + i - 4));
    const int pa = prevAct[row];
    const float4 ewA = *(const float4*)&embWr[(size_t)pa * G4 + N0 + tx * 4];
    const float4 ewB = *(const float4*)&embWr[(size_t)pa * G4 + N0 + 64 + tx * 4];
    {
      const float ig = acc[i][0] + ewA.x + brA.x;
      const float fg = acc[i][1] + ewA.y + brA.y;
      const float gg = acc[i][2] + ewA.z + brA.z;
      const float og = acc[i][3] + ewA.w + brA.w;
      const float cp = C[(size_t)row * H_ + uA];
      const float cn = sigm(fg) * cp + sigm(ig) * tanhf(gg);
      const float hn = sigm(og) * tanhf(cn);
      C[(size_t)row * H_ + uA] = cn;
      Hrow[(size_t)row * H_ + uA] = hn;
      hnA[i] = hn;
    }
    {
      const float ig = acc[i][4] + ewB.x + brB.x;
      const float fg = acc[i][5] + ewB.y + brB.y;
      const float gg = acc[i][6] + ewB.z + brB.z;
      const float og = acc[i][7] + ewB.w + brB.w;
      const float cp = C[(size_t)row * H_ + uB];
      const float cn = sigm(fg) * cp + sigm(ig) * tanhf(gg);
      const float hn = sigm(og) * tanhf(cn);
      C[(size_t)row * H_ + uB] = cn;
      Hrow[(size_t)row * H_ + uB] = hn;
      hnB[i] = hn;
    }
  }
  *(float4*)&HTout[(size_t)uA * B_ + M0 + ty * 4]      = make_float4(hnA[0], hnA[1], hnA[2], hnA[3]);
  *(float4*)&HTout[(size_t)uA * B_ + M0 + 64 + ty * 4] = make_float4(hnA[4], hnA[5], hnA[6], hnA[7]);
  *(float4*)&HTout[(size_t)uB * B_ + M0 + ty * 4]      = make_float4(hnB[0], hnB[1], hnB[2], hnB[3]);
  *(float4*)&HTout[(size_t)uB * B_ + M0 + 64 + ty * 4] = make_float4(hnB[4], hnB[5], hnB[6], hnB[7]);
}

// ---------------- per-step: logits, log-softmax, gumbel sample, outputs ----------------
__global__ __launch_bounds__(256) void k_sample(
    const float* __restrict__ Hnew, const float* __restrict__ WpT,
    const float* __restrict__ bp, float* __restrict__ out_msg,
    float* __restrict__ out_lp, int* __restrict__ stopped,
    int* __restrict__ prevAct, float* __restrict__ entSum,
    uint32_t key0, uint32_t key1, int t)
{
  const int lane = threadIdx.x & 63;
  const int b = blockIdx.x * 4 + (threadIdx.x >> 6);
  const float* hrow = Hnew + (size_t)b * H_;

  float acc = 0.f;
#pragma unroll 4
  for (int k4 = 0; k4 < H_; k4 += 4) {
    float4 hv = *(const float4*)(hrow + k4);
    acc = fmaf(hv.x, WpT[(k4 + 0) * 64 + lane], acc);
    acc = fmaf(hv.y, WpT[(k4 + 1) * 64 + lane], acc);
    acc = fmaf(hv.z, WpT[(k4 + 2) * 64 + lane], acc);
    acc = fmaf(hv.w, WpT[(k4 + 3) * 64 + lane], acc);
  }
  acc += bp[lane];                          // logits[b][lane]

  // log_softmax
  float m = acc;
#pragma unroll
  for (int o = 32; o > 0; o >>= 1) m = fmaxf(m, __shfl_xor(m, o, 64));
  float ex = expf(acc - m);
  float s = ex;
#pragma unroll
  for (int o = 32; o > 0; o >>= 1) s += __shfl_xor(s, o, 64);
  float logp = (acc - m) - logf(s);
  float p = expf(logp);
  float pe = p * logp;
  float es = pe;
#pragma unroll
  for (int o = 32; o > 0; o >>= 1) es += __shfl_xor(es, o, 64);
  float ent = -es;

  // gumbel: JAX partitionable threefry — 64-bit counter (0, j), bits = o0 ^ o1
  uint32_t j = (uint32_t)(b * 64 + lane);
  uint32_t o0, o1; tf2x32(key0, key1, 0u, j, o0, o1);
  uint32_t bits = o0 ^ o1;
  float f = __uint_as_float(0x3F800000u | (bits >> 9)) - 1.0f;
  const float TINY = 1.17549435e-38f;
  float u = fmaxf(TINY, f + TINY);
  float gum = -logf(-logf(u));
  float z = gum + acc;

  // argmax, first-index tie-break
  float best = z; int bi = lane;
#pragma unroll
  for (int o = 32; o > 0; o >>= 1) {
    float ov = __shfl_xor(best, o, 64);
    int oi = __shfl_xor(bi, o, 64);
    if (ov > best || (ov == best && oi < bi)) { best = ov; bi = oi; }
  }
  float lpa = __shfl(logp, bi, 64);

  if (lane == 0) {
    int st = stopped[b];
    float live = st ? 0.f : 1.f;
    int act = st ? PADT : bi;
    out_msg[(size_t)b * T_ + t] = (float)act;
    out_lp[(size_t)b * T_ + t] = live * lpa;
    entSum[b] += live * ent;
    stopped[b] = st | (act == 0);
    prevAct[b] = act;
  }
}

// ---------------- final: msg_len, ent_avg ----------------
__global__ void k_final(const float* __restrict__ out_msg, const float* __restrict__ entSum,
                        float* __restrict__ out_len, float* __restrict__ out_ent)
{
  int b = blockIdx.x * 256 + threadIdx.x;
  if (b >= B_) return;
  int cnt = 0;
#pragma unroll
  for (int t = 0; t < T_; t++) cnt += (out_msg[(size_t)b * T_ + t] != 64.0f) ? 1 : 0;
  out_len[b] = (float)cnt;
  out_ent[b] = entSum[b] / (float)cnt;
}

extern "C" void kernel_launch(void* const* d_in, const int* in_sizes, int n_in,
                              void* d_out, int out_size, void* d_ws, size_t ws_size,
                              hipStream_t stream)
{
  const float* enc = (const float*)d_in[0];
  const float* emb = (const float*)d_in[1];
  const float* Wih = (const float*)d_in[2];
  const float* Whh = (const float*)d_in[3];
  const float* bih = (const float*)d_in[4];
  const float* bhh = (const float*)d_in[5];
  const float* Wp  = (const float*)d_in[6];
  const float* bp  = (const float*)d_in[7];

  float* out_msg = (float*)d_out;            // [4096*16]
  float* out_len = out_msg + B_ * T_;        // [4096]
  float* out_lp  = out_len + B_;             // [4096*16]
  float* out_ent = out_lp + B_ * T_;         // [4096]

  float* w = (float*)d_ws;
  float* WrT   = w;  w += H_ * G4;           // [512][2048] 4MB
  float* embWr = w;  w += VOC * G4;
  float* br    = w;  w += G4;
  float* WpT   = w;  w += H_ * 64;
  float* hTA   = w;  w += H_ * B_;           // [512][4096] 8MB
  float* hTB   = w;  w += H_ * B_;           // 8MB
  float* hRow  = w;  w += B_ * H_;           // row-major h for sampling, 8MB
  float* cbuf  = w;  w += B_ * H_;           // 8MB
  float* entS  = w;  w += B_;
  int* stopped = (int*)w;  w += B_;
  int* prevAct = (int*)w;  w += B_;

  // step keys: partitionable threefry split — key[t] = threefry2x32((0,42), (0, t))
  uint32_t k0s[T_], k1s[T_];
  for (int t = 0; t < T_; t++) {
    uint32_t a, b2;
    tf2x32(0u, 42u, 0u, (uint32_t)t, a, b2);
    k0s[t] = a; k1s[t] = b2;
  }

  hipLaunchKernelGGL(k_prep, dim3((H_ * 64 + 255) / 256), dim3(256), 0, stream,
                     bih, bhh, Wp, br, WpT);
  hipLaunchKernelGGL(k_embw, dim3((VOC * G4 + 255) / 256), dim3(256), 0, stream,
                     emb, Wih, embWr);
  // WrT[k][n] = Whh[srow(n)][k]   (gate-interleaved, k-major)
  hipLaunchKernelGGL((k_transpose<1>), dim3(H_ / 64, G4 / 64), dim3(256), 0, stream,
                     Whh, WrT, G4, H_);
  // hTA[k][m] = enc[m][k]
  hipLaunchKernelGGL((k_transpose<0>), dim3(H_ / 64, B_ / 64), dim3(256), 0, stream,
                     enc, hTA, B_, H_);
  hipLaunchKernelGGL(k_init, dim3((B_ * H_ + 255) / 256), dim3(256), 0, stream,
                     enc, cbuf, stopped, prevAct, entS);

  for (int t = 0; t < T_; t++) {
    const float* hTin = (t & 1) ? hTB : hTA;
    float* hTout = (t & 1) ? hTA : hTB;
    hipLaunchKernelGGL(k_step, dim3(G4 / 128, B_ / 128), dim3(256), 0, stream,
                       hTin, WrT, embWr, br, prevAct, cbuf, hRow, hTout);
    hipLaunchKernelGGL(k_sample, dim3(B_ / 4), dim3(256), 0, stream,
                       hRow, WpT, bp, out_msg, out_lp, stopped, prevAct, entS,
                       k0s[t], k1s[t], t);
  }
  hipLaunchKernelGGL(k_final, dim3(B_ / 256), dim3(256), 0, stream,
                     out_msg, entS, out_len, out_ent);
}

// Round 8
// 2518.877 us; speedup vs baseline: 14.6994x; 1.2048x over previous
//
#include <hip/hip_runtime.h>
#include <stdint.h>

#define B_   4096
#define H_   512
#define G4   2048      // 4*H gates
#define T_   16
#define VOC  66
#define PADT 64
#define BOST 65

// ---------------- threefry2x32 (exact JAX partitionable schedule) ----------------
__host__ __device__ inline void tf2x32(uint32_t k0, uint32_t k1,
                                       uint32_t x0, uint32_t x1,
                                       uint32_t& o0, uint32_t& o1) {
  uint32_t ks2 = k0 ^ k1 ^ 0x1BD11BDAu;
  x0 += k0; x1 += k1;
  uint32_t ks[3] = {k1, ks2, k0};
  const int R[2][4] = {{13,15,26,6},{17,29,16,24}};
#pragma unroll
  for (int i = 0; i < 5; ++i) {
    const int* r = R[i & 1];
#pragma unroll
    for (int j = 0; j < 4; ++j) {
      x0 += x1;
      x1 = (x1 << r[j]) | (x1 >> (32 - r[j]));
      x1 ^= x0;
    }
    x0 += ks[0];
    x1 += ks[1] + (uint32_t)(i + 1);
    uint32_t tmp = ks[0]; ks[0] = ks[1]; ks[1] = ks[2]; ks[2] = tmp;
  }
  o0 = x0; o1 = x1;
}

__device__ inline float sigm(float x) { return 1.0f / (1.0f + expf(-x)); }

// global->LDS DMA, 16B per lane; LDS dest = wave-uniform base + lane*16
#define GLL16(gp, lp)                                                         \
  __builtin_amdgcn_global_load_lds(                                           \
      (const __attribute__((address_space(1))) void*)(gp),                    \
      (__attribute__((address_space(3))) void*)(lp), 16, 0, 0)

// ---------------- prep: fused biases (gate-interleaved), WpT ----------------
__global__ void k_prep(const float* __restrict__ bih, const float* __restrict__ bhh,
                       const float* __restrict__ Wp,
                       float* __restrict__ br, float* __restrict__ WpT)
{
  int idx = blockIdx.x * 256 + threadIdx.x;
  if (idx < G4) {
    int srow = ((idx & 3) << 9) + (idx >> 2);
    br[idx] = bih[srow] + bhh[srow];
  }
  if (idx < H_ * 64) {                       // WpT[k*64+a] = Wp[a*512+k]
    int k = idx >> 6, a = idx & 63;
    WpT[idx] = Wp[a * H_ + k];
  }
}

// ---------------- tiled transpose: out[c][r] = in[perm(r)][c] ----------------
// MODE 0: identity rows; MODE 1: gate-interleave perm srow(n)=((n&3)<<9)+(n>>2)
template<int MODE>
__global__ __launch_bounds__(256) void k_transpose(const float* __restrict__ in,
                                                   float* __restrict__ out,
                                                   int R, int C)
{
  __shared__ float tile[64][65];
  const int c0 = blockIdx.x * 64, r0 = blockIdx.y * 64;
  const int lx = threadIdx.x & 15, ly = threadIdx.x >> 4;
#pragma unroll
  for (int it = 0; it < 4; ++it) {
    int rr = ly + it * 16;
    int rlog = r0 + rr;
    int rphys = (MODE == 1) ? (((rlog & 3) << 9) + (rlog >> 2)) : rlog;
    float4 v = *(const float4*)&in[(size_t)rphys * C + c0 + lx * 4];
    tile[rr][lx * 4 + 0] = v.x; tile[rr][lx * 4 + 1] = v.y;
    tile[rr][lx * 4 + 2] = v.z; tile[rr][lx * 4 + 3] = v.w;
  }
  __syncthreads();
#pragma unroll
  for (int it = 0; it < 4; ++it) {
    int rr = ly + it * 16;
    float4 v = make_float4(tile[lx * 4 + 0][rr], tile[lx * 4 + 1][rr],
                           tile[lx * 4 + 2][rr], tile[lx * 4 + 3][rr]);
    *(float4*)&out[(size_t)(c0 + rr) * R + r0 + lx * 4] = v;
  }
}

// ---------------- embW = emb @ Wih^T, gate-interleaved columns ----------------
__global__ void k_embw(const float* __restrict__ emb, const float* __restrict__ Wih,
                       float* __restrict__ embWr)
{
  int idx = blockIdx.x * 256 + threadIdx.x;   // 66*2048
  if (idx >= VOC * G4) return;
  int a = idx >> 11, n = idx & (G4 - 1);
  int srow = ((n & 3) << 9) + (n >> 2);
  const float4* e = (const float4*)(emb + a * H_);
  const float4* w = (const float4*)(Wih + srow * H_);
  float s = 0.f;
#pragma unroll 4
  for (int k = 0; k < H_ / 4; ++k) {
    float4 ev = e[k], wv = w[k];
    s = fmaf(ev.x, wv.x, s); s = fmaf(ev.y, wv.y, s);
    s = fmaf(ev.z, wv.z, s); s = fmaf(ev.w, wv.w, s);
  }
  embWr[idx] = s;
}

// ---------------- init: c=encoded, flags ----------------
__global__ void k_init(const float* __restrict__ enc, float* __restrict__ c,
                       int* __restrict__ stopped, int* __restrict__ prevAct,
                       float* __restrict__ entSum)
{
  int i = blockIdx.x * 256 + threadIdx.x;
  if (i < B_ * H_) c[i] = enc[i];
  if (i < B_) { stopped[i] = 0; prevAct[i] = BOST; entSum[i] = 0.f; }
}

// ---------------- per-step: gates = h@Wr^T + embW[prev] + br ; fused LSTM cell ----------------
// HT: [512][4096] k-major h;  WT: [512][2048] k-major gate-interleaved Whh
// 256 threads, tile 128x128, frag 8x8 split-half, BK=16, double-buffered LDS.
// Staging via global_load_lds. ROUND-6 LESSON: the DMA issued at iter t into
// buf[nb] is consumed at iter t+1; the compiler does NOT reliably emit
// s_waitcnt vmcnt(0) before s_barrier for this structure -> latency race that
// opens when clocks ramp (cold pass, warm corrupt). Fix: explicit vmcnt(0)
// drain + sched_barrier pin immediately before every __syncthreads().
__global__ __launch_bounds__(256, 4) void k_step(
    const float* __restrict__ HT, const float* __restrict__ WT,
    const float* __restrict__ embWr, const float* __restrict__ br,
    const int* __restrict__ prevAct, float* __restrict__ C,
    float* __restrict__ Hrow, float* __restrict__ HTout)
{
  __shared__ float As[2][16][128];
  __shared__ float Bs[2][16][128];
  const int tid = threadIdx.x;
  const int tx = tid & 15;         // N-fragment slot
  const int ty = tid >> 4;         // M-fragment slot
  const int M0 = blockIdx.y * 128, N0 = blockIdx.x * 128;
  const int wv = tid >> 6;         // wave 0..3
  const int ln = tid & 63;
  // per-lane global source: row += ln>>5, col = (ln&31)*4 (16B, coalesced)
  const float* gA = HT + (size_t)(ln >> 5) * B_ + M0 + (ln & 31) * 4;
  const float* gB = WT + (size_t)(ln >> 5) * G4 + N0 + (ln & 31) * 4;

  float acc[8][8];
#pragma unroll
  for (int i = 0; i < 8; i++)
#pragma unroll
    for (int j = 0; j < 8; j++) acc[i][j] = 0.f;

  // prologue: DMA chunk 0 into buf 0
  {
    const int r = 4 * wv;
    GLL16(gA + (size_t)(r + 0) * B_, &As[0][r + 0][0]);
    GLL16(gA + (size_t)(r + 2) * B_, &As[0][r + 2][0]);
    GLL16(gB + (size_t)(r + 0) * G4, &Bs[0][r + 0][0]);
    GLL16(gB + (size_t)(r + 2) * G4, &Bs[0][r + 2][0]);
  }

#pragma unroll 1
  for (int t = 0; t < 32; ++t) {
    // explicit drain: this wave's chunk-t DMAs have landed in LDS before the
    // barrier; after the barrier ALL waves' chunk-t rows are readable.
    asm volatile("s_waitcnt vmcnt(0)" ::: "memory");
    __builtin_amdgcn_sched_barrier(0);
    __syncthreads();
    if (t < 31) {
      const int r = 4 * wv;
      const int k0 = (t + 1) * 16;
      const int nb = (t + 1) & 1;
      GLL16(gA + (size_t)(k0 + r + 0) * B_, &As[nb][r + 0][0]);
      GLL16(gA + (size_t)(k0 + r + 2) * B_, &As[nb][r + 2][0]);
      GLL16(gB + (size_t)(k0 + r + 0) * G4, &Bs[nb][r + 0][0]);
      GLL16(gB + (size_t)(k0 + r + 2) * G4, &Bs[nb][r + 2][0]);
    }
    const int cur = t & 1;
#pragma unroll
    for (int kk = 0; kk < 16; ++kk) {
      const float4 a0 = *(const float4*)&As[cur][kk][ty * 4];
      const float4 a1 = *(const float4*)&As[cur][kk][ty * 4 + 64];
      const float4 b0 = *(const float4*)&Bs[cur][kk][tx * 4];
      const float4 b1 = *(const float4*)&Bs[cur][kk][tx * 4 + 64];
      const float av[8] = {a0.x, a0.y, a0.z, a0.w, a1.x, a1.y, a1.z, a1.w};
      const float bv[8] = {b0.x, b0.y, b0.z, b0.w, b1.x, b1.y, b1.z, b1.w};
#pragma unroll
      for (int i = 0; i < 8; i++)
#pragma unroll
        for (int j = 0; j < 8; j++) acc[i][j] = fmaf(av[i], bv[j], acc[i][j]);
    }
  }

  // epilogue: gates -> LSTM cell -> C, Hrow, HTout
  const int uA = (N0 >> 2) + tx;
  const int uB = uA + 16;
  const float4 brA = *(const float4*)&br[N0 + tx * 4];
  const float4 brB = *(const float4*)&br[N0 + 64 + tx * 4];
  float hnA[8], hnB[8];
#pragma unroll
  for (int i = 0; i < 8; ++i) {
    const int row = M0 + ((i < 4) ? (ty * 4 + i) : (64 + ty * 4 + i - 4));
    const int pa = prevAct[row];
    const float4 ewA = *(const float4*)&embWr[(size_t)pa * G4 + N0 + tx * 4];
    const float4 ewB = *(const float4*)&embWr[(size_t)pa * G4 + N0 + 64 + tx * 4];
    {
      const float ig = acc[i][0] + ewA.x + brA.x;
      const float fg = acc[i][1] + ewA.y + brA.y;
      const float gg = acc[i][2] + ewA.z + brA.z;
      const float og = acc[i][3] + ewA.w + brA.w;
      const float cp = C[(size_t)row * H_ + uA];
      const float cn = sigm(fg) * cp + sigm(ig) * tanhf(gg);
      const float hn = sigm(og) * tanhf(cn);
      C[(size_t)row * H_ + uA] = cn;
      Hrow[(size_t)row * H_ + uA] = hn;
      hnA[i] = hn;
    }
    {
      const float ig = acc[i][4] + ewB.x + brB.x;
      const float fg = acc[i][5] + ewB.y + brB.y;
      const float gg = acc[i][6] + ewB.z + brB.z;
      const float og = acc[i][7] + ewB.w + brB.w;
      const float cp = C[(size_t)row * H_ + uB];
      const float cn = sigm(fg) * cp + sigm(ig) * tanhf(gg);
      const float hn = sigm(og) * tanhf(cn);
      C[(size_t)row * H_ + uB] = cn;
      Hrow[(size_t)row * H_ + uB] = hn;
      hnB[i] = hn;
    }
  }
  *(float4*)&HTout[(size_t)uA * B_ + M0 + ty * 4]      = make_float4(hnA[0], hnA[1], hnA[2], hnA[3]);
  *(float4*)&HTout[(size_t)uA * B_ + M0 + 64 + ty * 4] = make_float4(hnA[4], hnA[5], hnA[6], hnA[7]);
  *(float4*)&HTout[(size_t)uB * B_ + M0 + ty * 4]      = make_float4(hnB[0], hnB[1], hnB[2], hnB[3]);
  *(float4*)&HTout[(size_t)uB * B_ + M0 + 64 + ty * 4] = make_float4(hnB[4], hnB[5], hnB[6], hnB[7]);
}

// ---------------- per-step: logits, log-softmax, gumbel sample, outputs ----------------
__global__ __launch_bounds__(256) void k_sample(
    const float* __restrict__ Hnew, const float* __restrict__ WpT,
    const float* __restrict__ bp, float* __restrict__ out_msg,
    float* __restrict__ out_lp, int* __restrict__ stopped,
    int* __restrict__ prevAct, float* __restrict__ entSum,
    uint32_t key0, uint32_t key1, int t)
{
  const int lane = threadIdx.x & 63;
  const int b = blockIdx.x * 4 + (threadIdx.x >> 6);
  const float* hrow = Hnew + (size_t)b * H_;

  float acc = 0.f;
#pragma unroll 4
  for (int k4 = 0; k4 < H_; k4 += 4) {
    float4 hv = *(const float4*)(hrow + k4);
    acc = fmaf(hv.x, WpT[(k4 + 0) * 64 + lane], acc);
    acc = fmaf(hv.y, WpT[(k4 + 1) * 64 + lane], acc);
    acc = fmaf(hv.z, WpT[(k4 + 2) * 64 + lane], acc);
    acc = fmaf(hv.w, WpT[(k4 + 3) * 64 + lane], acc);
  }
  acc += bp[lane];                          // logits[b][lane]

  // log_softmax
  float m = acc;
#pragma unroll
  for (int o = 32; o > 0; o >>= 1) m = fmaxf(m, __shfl_xor(m, o, 64));
  float ex = expf(acc - m);
  float s = ex;
#pragma unroll
  for (int o = 32; o > 0; o >>= 1) s += __shfl_xor(s, o, 64);
  float logp = (acc - m) - logf(s);
  float p = expf(logp);
  float pe = p * logp;
  float es = pe;
#pragma unroll
  for (int o = 32; o > 0; o >>= 1) es += __shfl_xor(es, o, 64);
  float ent = -es;

  // gumbel: JAX partitionable threefry — 64-bit counter (0, j), bits = o0 ^ o1
  uint32_t j = (uint32_t)(b * 64 + lane);
  uint32_t o0, o1; tf2x32(key0, key1, 0u, j, o0, o1);
  uint32_t bits = o0 ^ o1;
  float f = __uint_as_float(0x3F800000u | (bits >> 9)) - 1.0f;
  const float TINY = 1.17549435e-38f;
  float u = fmaxf(TINY, f + TINY);
  float gum = -logf(-logf(u));
  float z = gum + acc;

  // argmax, first-index tie-break
  float best = z; int bi = lane;
#pragma unroll
  for (int o = 32; o > 0; o >>= 1) {
    float ov = __shfl_xor(best, o, 64);
    int oi = __shfl_xor(bi, o, 64);
    if (ov > best || (ov == best && oi < bi)) { best = ov; bi = oi; }
  }
  float lpa = __shfl(logp, bi, 64);

  if (lane == 0) {
    int st = stopped[b];
    float live = st ? 0.f : 1.f;
    int act = st ? PADT : bi;
    out_msg[(size_t)b * T_ + t] = (float)act;
    out_lp[(size_t)b * T_ + t] = live * lpa;
    entSum[b] += live * ent;
    stopped[b] = st | (act == 0);
    prevAct[b] = act;
  }
}

// ---------------- final: msg_len, ent_avg ----------------
__global__ void k_final(const float* __restrict__ out_msg, const float* __restrict__ entSum,
                        float* __restrict__ out_len, float* __restrict__ out_ent)
{
  int b = blockIdx.x * 256 + threadIdx.x;
  if (b >= B_) return;
  int cnt = 0;
#pragma unroll
  for (int t = 0; t < T_; t++) cnt += (out_msg[(size_t)b * T_ + t] != 64.0f) ? 1 : 0;
  out_len[b] = (float)cnt;
  out_ent[b] = entSum[b] / (float)cnt;
}

extern "C" void kernel_launch(void* const* d_in, const int* in_sizes, int n_in,
                              void* d_out, int out_size, void* d_ws, size_t ws_size,
                              hipStream_t stream)
{
  const float* enc = (const float*)d_in[0];
  const float* emb = (const float*)d_in[1];
  const float* Wih = (const float*)d_in[2];
  const float* Whh = (const float*)d_in[3];
  const float* bih = (const float*)d_in[4];
  const float* bhh = (const float*)d_in[5];
  const float* Wp  = (const float*)d_in[6];
  const float* bp  = (const float*)d_in[7];

  float* out_msg = (float*)d_out;            // [4096*16]
  float* out_len = out_msg + B_ * T_;        // [4096]
  float* out_lp  = out_len + B_;             // [4096*16]
  float* out_ent = out_lp + B_ * T_;         // [4096]

  float* w = (float*)d_ws;
  float* WrT   = w;  w += H_ * G4;           // [512][2048] 4MB
  float* embWr = w;  w += VOC * G4;
  float* br    = w;  w += G4;
  float* WpT   = w;  w += H_ * 64;
  float* hTA   = w;  w += H_ * B_;           // [512][4096] 8MB
  float* hTB   = w;  w += H_ * B_;           // 8MB
  float* hRow  = w;  w += B_ * H_;           // row-major h for sampling, 8MB
  float* cbuf  = w;  w += B_ * H_;           // 8MB
  float* entS  = w;  w += B_;
  int* stopped = (int*)w;  w += B_;
  int* prevAct = (int*)w;  w += B_;

  // step keys: partitionable threefry split — key[t] = threefry2x32((0,42), (0, t))
  uint32_t k0s[T_], k1s[T_];
  for (int t = 0; t < T_; t++) {
    uint32_t a, b2;
    tf2x32(0u, 42u, 0u, (uint32_t)t, a, b2);
    k0s[t] = a; k1s[t] = b2;
  }

  hipLaunchKernelGGL(k_prep, dim3((H_ * 64 + 255) / 256), dim3(256), 0, stream,
                     bih, bhh, Wp, br, WpT);
  hipLaunchKernelGGL(k_embw, dim3((VOC * G4 + 255) / 256), dim3(256), 0, stream,
                     emb, Wih, embWr);
  // WrT[k][n] = Whh[srow(n)][k]   (gate-interleaved, k-major)
  hipLaunchKernelGGL((k_transpose<1>), dim3(H_ / 64, G4 / 64), dim3(256), 0, stream,
                     Whh, WrT, G4, H_);
  // hTA[k][m] = enc[m][k]
  hipLaunchKernelGGL((k_transpose<0>), dim3(H_ / 64, B_ / 64), dim3(256), 0, stream,
                     enc, hTA, B_, H_);
  hipLaunchKernelGGL(k_init, dim3((B_ * H_ + 255) / 256), dim3(256), 0, stream,
                     enc, cbuf, stopped, prevAct, entS);

  for (int t = 0; t < T_; t++) {
    const float* hTin = (t & 1) ? hTB : hTA;
    float* hTout = (t & 1) ? hTA : hTB;
    hipLaunchKernelGGL(k_step, dim3(G4 / 128, B_ / 128), dim3(256), 0, stream,
                       hTin, WrT, embWr, br, prevAct, cbuf, hRow, hTout);
    hipLaunchKernelGGL(k_sample, dim3(B_ / 4), dim3(256), 0, stream,
                       hRow, WpT, bp, out_msg, out_lp, stopped, prevAct, entS,
                       k0s[t], k1s[t], t);
  }
  hipLaunchKernelGGL(k_final, dim3(B_ / 256), dim3(256), 0, stream,
                     out_msg, entS, out_len, out_ent);
}